// Round 23
// baseline (87.491 us; speedup 1.0000x reference)
//
#include <hip/hip_runtime.h>
#include <stdint.h>
#include <stddef.h>

typedef unsigned short u16;
typedef unsigned int u32;
typedef __attribute__((ext_vector_type(8))) __bf16 bf16x8;
typedef __attribute__((ext_vector_type(4))) float f32x4;
typedef __attribute__((ext_vector_type(16))) float f32x16;

#define DEV __device__ __forceinline__

// ---- problem dims (hardcoded per reference) ----
#define BATCH 2
#define SEQ   2048
#define CDIM  1024
#define NH    16
#define KD    64
#define MROWS (BATCH * SEQ)   // 4096
#define NX (MROWS * CDIM)     // 4194304
#define NW (CDIM * CDIM)      // 1048576
#define BHSZ  131072          // SEQ*KD u16 per (b,h)

DEV u16 f32_to_bf16(float f) {
  union { float f; unsigned u; } v; v.f = f;
  return (u16)((v.u + 0x7fffu + ((v.u >> 16) & 1u)) >> 16);
}
DEV u32 pack_bf16x2(float a, float b) {
  union { __bf16 h[2]; u32 u; } r;
  r.h[0] = (__bf16)a; r.h[1] = (__bf16)b;
  return r.u;
}
// truncation pack: low16 = hi16(a), high16 = hi16(b) -- single v_perm_b32
DEV u32 pack_trunc(float a, float b) {
  return __builtin_amdgcn_perm(__float_as_uint(b), __float_as_uint(a), 0x07060302u);
}
// raw 2^x (single v_exp_f32, no OCML wrapper)
DEV float v_exp2(float x) {
  float r; asm("v_exp_f32 %0, %1" : "=v"(r) : "v"(x)); return r;
}

// async global->LDS, 16B per lane
DEV void gl_lds16(const u16* g, u16* l) {
  __builtin_amdgcn_global_load_lds(
      (const __attribute__((address_space(1))) void*)(g),
      (__attribute__((address_space(3))) void*)(l), 16, 0, 0);
}

// ======================= fragment-linear layouts ==========================
// Kf stores K rows SIGMA-PERMUTED within each 32-row group (sigma = swap bits 2<->3
// of local kv, self-inverse): QK's S^T registers line up so s[8*ksl..8*ksl+7] IS the
// PV B-fragment pa[ksl] -- no cross-half exchange.
// Vf[bh][tile64][j=ksg*2+dh ][lane][8] = proj[tile64*64 + ksg*16 + (lane>>5)*8 + i][dh*32 + (lane&31)]
// Qf[bh][chunk][kc][lane][8]           = qm [chunk*32 + (lane&31)][kc*16 + (lane>>5)*8 + i] * cl2

// ---- fused: f32->bf16 convert of W_proj/W_mix (blocks 0..511) + metric (512..767) --
// x is no longer pre-converted: gemm<0> consumes f32 x directly (fused staging).
__global__ void cvt_metric(const float* __restrict__ wp, const float* __restrict__ wm,
                           const float* __restrict__ pm,
                           u16* __restrict__ wpb, u16* __restrict__ wmb,
                           u16* __restrict__ metric) {
  __shared__ float P[64][65];
  int bid = blockIdx.x, t = threadIdx.x;
  if (bid < 512) {
    int total4 = (2 * NW) >> 2;
    for (int i4 = bid * 256 + t; i4 < total4; i4 += 512 * 256) {
      int i = i4 << 2;
      const float* src; u16* dst; int off;
      if (i < NW) { src = wp; dst = wpb; off = i; }
      else        { src = wm; dst = wmb; off = i - NW; }
      float4 v = *reinterpret_cast<const float4*>(src + off);
      uint2 o;          // truncation: 2 v_perm instead of ~20 VALU for RNE
      o.x = pack_trunc(v.x, v.y);
      o.y = pack_trunc(v.z, v.w);
      *reinterpret_cast<uint2*>(dst + off) = o;
    }
    return;
  }
  int mb = bid - 512;
  int h = mb >> 4, jgrp = mb & 15;
  if (t < 64) {
    int i = t;
    const float* row = pm + (size_t)(h * 64 + i) * 64;
    float mx = -1e30f;
    for (int j = 0; j <= i; ++j) mx = fmaxf(mx, row[j] * 0.125f);
    float s = 0.f;
    for (int j = 0; j <= i; ++j) { float e = expf(row[j] * 0.125f - mx); P[i][j] = e; s += e; }
    float inv = 1.f / s;
    for (int j = 0; j <= i; ++j) P[i][j] *= inv;
    for (int j = i + 1; j < 64; ++j) P[i][j] = 0.f;
  }
  __syncthreads();
  {
    int i = t & 63, jq = t >> 6;
    int j = jgrp * 4 + jq;
    float acc = 0.f;
    #pragma unroll
    for (int l = 0; l < 64; ++l) acc += P[i][l] * P[j][l];
    metric[(size_t)h * 4096 + i * 64 + j] = f32_to_bf16(acc);
  }
}

// ---------------- bf16 MFMA GEMM: C = A @ B^T, 128Mx64N tile, BK=64, 512 blocks ----
// GRID AXES SWAPPED (T1): XCD = M-tile % 8 -> per-XCD L2 keeps its A-panels + full B.
// T3-minimum 2-phase double-buffer; one barrier per k-step. LDS XOR-swizzled (T2).
// MODE 0: A is **f32 x** -- fused convert-during-staging (T14 split: issue f32 loads,
//         compute, trunc-pack + swizzled ds_write, barrier). N-tile == one head;
//         writes Kf (sigma lane slots) / Vf (uint2-packed) + fused qm -> Qf.
// MODE 1: A is bf16 (nudged); gl_lds16 staging; f32 C0 output.
template <int MODE>
__launch_bounds__(256)
__global__ void gemm_xwt(const u16* __restrict__ A, const u16* __restrict__ B,
                         void* __restrict__ C0, u16* __restrict__ C1,
                         const u16* __restrict__ Mbf, u16* __restrict__ Qf,
                         int M, int N, int K) {
  __shared__ __align__(16) u16 SM[2 * 12288];   // 48KB: 2 x (A[128][64] + B[64][64])
  int bm0 = blockIdx.x * 128, bn0 = blockIdx.y * 64;
  int t = threadIdx.x, wv = t >> 6, lane = t & 63;
  int l15 = lane & 15, l4 = lane >> 4;
  f32x4 acc[2][4] = {};

  const int r8 = lane >> 3;                 // 0..7 (row within 8-row group)
  const int sseg = ((lane & 7) ^ r8) * 8;   // swizzled column (u16 units)
  const float* Af = reinterpret_cast<const float*>(A);   // MODE 0: f32 source

  float4 va[4][2];   // MODE 0: in-flight f32 A data (T14 issue-early/write-late)

  auto ldA0 = [&](int k0) {
    #pragma unroll
    for (int q = 0; q < 4; ++q) {
      int rowf = q * 32 + wv * 8 + r8;
      const float* src = Af + (size_t)(bm0 + rowf) * K + k0 + (lane & 7) * 8;
      va[q][0] = *reinterpret_cast<const float4*>(src);
      va[q][1] = *reinterpret_cast<const float4*>(src + 4);
    }
  };
  auto stA0 = [&](u16* dst) {
    #pragma unroll
    for (int q = 0; q < 4; ++q) {
      int rowf = q * 32 + wv * 8 + r8;
      uint4 pk4;
      pk4.x = pack_trunc(va[q][0].x, va[q][0].y);
      pk4.y = pack_trunc(va[q][0].z, va[q][0].w);
      pk4.z = pack_trunc(va[q][1].x, va[q][1].y);
      pk4.w = pack_trunc(va[q][1].z, va[q][1].w);
      *reinterpret_cast<uint4*>(dst + rowf * 64 + sseg) = pk4;  // LDS[row][s^=row&7]
    }
  };
  auto stageA1 = [&](int k0, u16* dst) {
    #pragma unroll
    for (int q = 0; q < 4; ++q) {
      int rowl = q * 32 + wv * 8;
      gl_lds16(A + (size_t)(bm0 + rowl + r8) * K + k0 + sseg, dst + rowl * 64);
    }
  };
  auto stageB = [&](int k0, u16* dst) {
    u16* dstB = dst + 8192;
    #pragma unroll
    for (int q = 0; q < 2; ++q) {
      int rowl = q * 32 + wv * 8;
      gl_lds16(B + (size_t)(bn0 + rowl + r8) * K + k0 + sseg, dstB + rowl * 64);
    }
  };

  if (MODE == 0) { ldA0(0); stageB(0, SM); stA0(SM); }
  else           { stageA1(0, SM); stageB(0, SM); }
  __syncthreads();
  const int NKS = K >> 6;
  for (int ks = 0; ks < NKS; ++ks) {
    u16* cur = SM + (ks & 1) * 12288;
    u16* nxt = SM + ((ks + 1) & 1) * 12288;
    if (ks + 1 < NKS) {
      if (MODE == 0) { ldA0((ks + 1) * 64); stageB((ks + 1) * 64, nxt); }
      else           { stageA1((ks + 1) * 64, nxt); stageB((ks + 1) * 64, nxt); }
    }
    const u16* As = cur;
    const u16* Bs = cur + 8192;
    #pragma unroll
    for (int kk = 0; kk < 2; ++kk) {
      bf16x8 af[2], bfm[4];
      #pragma unroll
      for (int m = 0; m < 2; ++m) {
        int R = wv * 32 + m * 16 + l15;
        af[m] = *reinterpret_cast<const bf16x8*>(As + R * 64 + ((kk * 4 + l4) ^ (R & 7)) * 8);
      }
      #pragma unroll
      for (int nn = 0; nn < 4; ++nn) {
        int R = nn * 16 + l15;
        bfm[nn] = *reinterpret_cast<const bf16x8*>(Bs + R * 64 + ((kk * 4 + l4) ^ (R & 7)) * 8);
      }
      #pragma unroll
      for (int m = 0; m < 2; ++m)
        #pragma unroll
        for (int nn = 0; nn < 4; ++nn)
          acc[m][nn] = __builtin_amdgcn_mfma_f32_16x16x32_bf16(af[m], bfm[nn], acc[m][nn], 0, 0, 0);
    }
    if (MODE == 0 && ks + 1 < NKS) stA0(nxt);   // write-late: loads flew under MFMAs
    __syncthreads();
  }

  if (MODE == 0) {
    int h = bn0 >> 6, bb = bm0 >> 11;
    size_t base = (size_t)(bb * NH + h) * BHSZ;
    u16* Pl = SM;            // [128][72] bf16 proj tile (A-frags for qm)
    u16* Ml = SM + 9216;     // [64][72]  bf16 metric    (B-frags for qm)
    // stage metric[h] into LDS (safe: k-loop ended with barrier)
    #pragma unroll
    for (int it = 0; it < 2; ++it) {
      int i = t * 8 + it * 2048;
      int r = i >> 6, c8 = i & 63;
      *reinterpret_cast<uint4*>(Ml + r * 72 + c8) =
          *reinterpret_cast<const uint4*>(Mbf + h * 4096 + i);
    }
    // fragment stores: Kf (sigma lane slots), Vf (uint2-packed) + P tile (LDS)
    #pragma unroll
    for (int m = 0; m < 2; ++m) {
      #pragma unroll
      for (int nn = 0; nn < 4; ++nn) {
        u16 hv4[4];
        #pragma unroll
        for (int rr = 0; rr < 4; ++rr) {
          int rowl = wv * 32 + m * 16 + l4 * 4 + rr;      // local row 0..127
          int d = nn * 16 + l15;
          u16 hv = f32_to_bf16(acc[m][nn][rr]);
          hv4[rr] = hv;
          int w2 = (bm0 & 2047) + rowl;
          int tile = w2 >> 6, rt = w2 & 63;
          int rl = rt & 31;
          // sigma: swap bits 2<->3 of local kv (self-inverse)
          int rls = (rl & 19) | ((rl & 4) << 1) | ((rl & 8) >> 1);
          // Kf: j=(d>>4)*2+(rt>>5), l=rls|(((d>>3)&1)<<5), i=d&7
          ((u16*)C0)[base + (size_t)(tile * 8 + (d >> 4) * 2 + (rt >> 5)) * 512
                     + (rls | (((d >> 3) & 1) << 5)) * 8 + (d & 7)] = hv;
          Pl[rowl * 72 + d] = hv;
        }
        // Vf packed: i = rt&7 contiguous across rr; one 8B store replaces 4 scatters
        {
          int rowl0 = wv * 32 + m * 16 + l4 * 4;
          int d = nn * 16 + l15;
          int w20 = (bm0 & 2047) + rowl0;
          int tile = w20 >> 6, rt0 = w20 & 63;
          uint2 vv;
          vv.x = (u32)hv4[0] | ((u32)hv4[1] << 16);
          vv.y = (u32)hv4[2] | ((u32)hv4[3] << 16);
          *reinterpret_cast<uint2*>(
              C1 + base + (size_t)(tile * 8 + ((rt0 >> 4) & 3) * 2 + (d >> 5)) * 512
                 + ((d & 31) | (((rt0 >> 3) & 1) << 5)) * 8 + (rt0 & 7)) = vv;
        }
      }
    }
    __syncthreads();
    // fused qm: qm_tile = P[128x64] @ M[64x64] (M symmetric -> B-frags = M rows)
    const float cl2 = 0.125f * 1.44269504088896f;
    f32x4 acc2[2][4] = {};
    #pragma unroll
    for (int kk2 = 0; kk2 < 2; ++kk2) {
      bf16x8 af2[2], bm2[4];
      #pragma unroll
      for (int m = 0; m < 2; ++m)
        af2[m] = *reinterpret_cast<const bf16x8*>(Pl + (wv * 32 + m * 16 + l15) * 72 + kk2 * 32 + l4 * 8);
      #pragma unroll
      for (int nn = 0; nn < 4; ++nn)
        bm2[nn] = *reinterpret_cast<const bf16x8*>(Ml + (nn * 16 + l15) * 72 + kk2 * 32 + l4 * 8);
      #pragma unroll
      for (int m = 0; m < 2; ++m)
        #pragma unroll
        for (int nn = 0; nn < 4; ++nn)
          acc2[m][nn] = __builtin_amdgcn_mfma_f32_16x16x32_bf16(af2[m], bm2[nn], acc2[m][nn], 0, 0, 0);
    }
    // Qf scatter store (pre-scaled by cl2)
    #pragma unroll
    for (int m = 0; m < 2; ++m) {
      #pragma unroll
      for (int nn = 0; nn < 4; ++nn) {
        #pragma unroll
        for (int rr = 0; rr < 4; ++rr) {
          int rowl = wv * 32 + m * 16 + l4 * 4 + rr;
          int d = nn * 16 + l15;
          int w2 = (bm0 & 2047) + rowl;
          Qf[base + (size_t)((w2 >> 5) * 4 + (d >> 4)) * 512
             + ((w2 & 31) | (((d >> 3) & 1) << 5)) * 8 + (d & 7)]
              = f32_to_bf16(acc2[m][nn][rr] * cl2);
        }
      }
    }
  } else {
    #pragma unroll
    for (int m = 0; m < 2; ++m) {
      int rbase = bm0 + wv * 32 + m * 16 + l4 * 4;
      #pragma unroll
      for (int nn = 0; nn < 4; ++nn) {
        int col = bn0 + nn * 16 + l15;
        #pragma unroll
        for (int rr = 0; rr < 4; ++rr)
          ((float*)C0)[(size_t)(rbase + rr) * N + col] = acc[m][nn][rr];
      }
    }
  }
}

// ---------------- causal flash attention: KVBLK=32, 4-way kv split, one chunk/block --
// grid (32 bh, 64 chunk [LPT]); bh -> XCD affinity optimal (32 % 8 == 0).
// sigma-permuted Kf => s[8*ksl..8*ksl+7] IS the PV B-frag: no exchange, no shfl.
// Groupwise softmax->PV (R21-proven best; R17/R20/R22 in-wave variants all neutral).
// __launch_bounds__(256,4): 128-unified-reg cap -> 4 waves/SIMD (R18-validated).
__launch_bounds__(256, 4)
__global__ void attn_kernel(const u16* __restrict__ Qf, const u16* __restrict__ Kf,
                            const u16* __restrict__ Vf, u16* __restrict__ nudged) {
  const int bh = blockIdx.x;
  const int bb = bh >> 4, h = bh & 15;
  const int p = 63 - (int)blockIdx.y;      // chunk (longest dispatched first)
  const int t = threadIdx.x, wv = t >> 6, lane = t & 63;
  const int c = lane & 31, hi = lane >> 5;
  const int q0 = p * 32;

  __shared__ float smf[4][2176];   // per warp: O^T[64][33] + l[32]@2112

  const u16* __restrict__ Kbh = Kf + (size_t)bh * BHSZ;
  const u16* __restrict__ Vbh = Vf + (size_t)bh * BHSZ;

  // Q fragments (coalesced 16B/lane), pre-scaled by cl2
  bf16x8 qf[4];
  {
    const u16* __restrict__ Qb = Qf + (size_t)bh * BHSZ + p * 2048 + lane * 8;
    #pragma unroll
    for (int kc = 0; kc < 4; ++kc)
      qf[kc] = *reinterpret_cast<const bf16x8*>(Qb + kc * 512);
  }

  f32x16 o0 = {}, o1 = {};
  float sv0 = 0.f, sv1 = 0.f;

  const int half = wv & 1;
  // current-tile offsets into Kf / Vf (u16 units); tile T: tile64 = T>>1
  u32 koff = (u32)((wv >> 1) * 4096 + half * 512 + lane * 8);
  u32 voff = (u32)((wv >> 1) * 4096 + half * 2048 + lane * 8);

  bf16x8 kf[4], vf0[2], vf1[2];
  if (wv <= p) {
    #pragma unroll
    for (int kc = 0; kc < 4; ++kc)
      kf[kc] = *reinterpret_cast<const bf16x8*>(Kbh + koff + kc * 1024);
    #pragma unroll
    for (int ksl = 0; ksl < 2; ++ksl) {
      vf0[ksl] = *reinterpret_cast<const bf16x8*>(Vbh + voff + ksl * 1024);
      vf1[ksl] = *reinterpret_cast<const bf16x8*>(Vbh + voff + ksl * 1024 + 512);
    }
  }

  for (int T = wv; T <= p; T += 4) {
    // S^T[kv=32][q=32] = K @ qm^T (lane c owns q-col c; rows sigma-permuted)
    f32x16 s = {};
    __builtin_amdgcn_s_setprio(1);
    #pragma unroll
    for (int kc = 0; kc < 4; ++kc)
      s = __builtin_amdgcn_mfma_f32_32x32x16_bf16(kf[kc], qf[kc], s, 0, 0, 0);
    __builtin_amdgcn_s_setprio(0);
    // K-regs dead: reload next tile now (in flight under softmax + PV)
    if (T + 4 <= p) {
      #pragma unroll
      for (int kc = 0; kc < 4; ++kc)
        kf[kc] = *reinterpret_cast<const bf16x8*>(Kbh + koff + 8192 + kc * 1024);
    }
    // causal mask (diagonal tile only): s[r] holds kv = sigma(row) per lane
    if (T == p) {
      #pragma unroll
      for (int r = 0; r < 16; ++r) {
        int kvl = (r & 3) + 4 * ((r >> 2) & 1) + 8 * hi + 16 * (r >> 3);
        if (kvl > c) s[r] = -1e30f;
      }
    }
    // groupwise softmax+PV: process ksl group 0 fully, then group 1.
    #pragma unroll
    for (int ksl = 0; ksl < 2; ++ksl) {
      float a = v_exp2(s[ksl * 8 + 0]);
      float b = v_exp2(s[ksl * 8 + 1]);
      float cc = v_exp2(s[ksl * 8 + 2]);
      float d = v_exp2(s[ksl * 8 + 3]);
      float e = v_exp2(s[ksl * 8 + 4]);
      float f = v_exp2(s[ksl * 8 + 5]);
      float g2 = v_exp2(s[ksl * 8 + 6]);
      float h2 = v_exp2(s[ksl * 8 + 7]);
      union { u32 u[4]; bf16x8 v; } pk;
      pk.u[0] = pack_trunc(a, b);
      pk.u[1] = pack_trunc(cc, d);
      pk.u[2] = pack_trunc(e, f);
      pk.u[3] = pack_trunc(g2, h2);
      __builtin_amdgcn_s_setprio(1);
      o0 = __builtin_amdgcn_mfma_f32_32x32x16_bf16(vf0[ksl], pk.v, o0, 0, 0, 0);
      o1 = __builtin_amdgcn_mfma_f32_32x32x16_bf16(vf1[ksl], pk.v, o1, 0, 0, 0);
      __builtin_amdgcn_s_setprio(0);
      sv0 += (a + b) + (cc + d);
      sv1 += (e + f) + (g2 + h2);
    }
    // V-regs dead: reload next tile now (in flight under next QK)
    if (T + 4 <= p) {
      #pragma unroll
      for (int ksl = 0; ksl < 2; ++ksl) {
        vf0[ksl] = *reinterpret_cast<const bf16x8*>(Vbh + voff + 8192 + ksl * 1024);
        vf1[ksl] = *reinterpret_cast<const bf16x8*>(Vbh + voff + 8192 + ksl * 1024 + 512);
      }
    }
    koff += 8192; voff += 8192;
  }

  // per-q-row sum (cross-half: other 16 kv of this q live in partner lane)
  float lrow;
  {
    float s2 = sv0 + sv1;
    lrow = s2 + __shfl_xor(s2, 32);
  }

  // ---- publish partials, then all-thread 4-way merge + coalesced store ----
  {
    float* Ob = smf[wv];
    #pragma unroll
    for (int r = 0; r < 16; ++r) {
      int d = (r & 3) + 8 * (r >> 2) + 4 * hi;
      Ob[d * 33 + c] = o0[r];
      Ob[(d + 32) * 33 + c] = o1[r];
    }
    if (hi == 0) Ob[2112 + c] = lrow;
  }
  __syncthreads();
  {
    int q = t >> 3, dseg = t & 7;
    float lsum = smf[0][2112 + q] + smf[1][2112 + q] + smf[2][2112 + q] + smf[3][2112 + q];
    float invd = 1.f / lsum;
    u16 outv[8];
    #pragma unroll
    for (int i2 = 0; i2 < 8; ++i2) {
      int d = dseg * 8 + i2;
      float v = smf[0][d * 33 + q] + smf[1][d * 33 + q] + smf[2][d * 33 + q] + smf[3][d * 33 + q];
      outv[i2] = f32_to_bf16(v * invd);
    }
    u16* dstp = nudged + ((size_t)bb * SEQ + q0 + q) * CDIM + h * KD + dseg * 8;
    uint4 ov;
    ov.x = (u32)outv[0] | ((u32)outv[1] << 16);
    ov.y = (u32)outv[2] | ((u32)outv[3] << 16);
    ov.z = (u32)outv[4] | ((u32)outv[5] << 16);
    ov.w = (u32)outv[6] | ((u32)outv[7] << 16);
    *reinterpret_cast<uint4*>(dstp) = ov;
  }
}

// ---------------- host launch ----------------
extern "C" void kernel_launch(void* const* d_in, const int* in_sizes, int n_in,
                              void* d_out, int out_size, void* d_ws, size_t ws_size,
                              hipStream_t stream) {
  (void)in_sizes; (void)n_in; (void)out_size; (void)ws_size;
  const float* x      = (const float*)d_in[0];
  const float* Wproj  = (const float*)d_in[1];
  const float* premet = (const float*)d_in[2];
  const float* Wmix   = (const float*)d_in[3];

  char* w = (char*)d_ws;
  u16* wp_bf  = (u16*)w;  w += (size_t)CDIM * CDIM * 2;         // 2 MB
  u16* wm_bf  = (u16*)w;  w += (size_t)CDIM * CDIM * 2;         // 2 MB
  u16* metric = (u16*)w;  w += (size_t)NH * KD * KD * 2;        // 128 KB
  u16* Kf     = (u16*)w;  w += (size_t)BATCH * NH * BHSZ * 2;   // 8 MB
  u16* Vf     = (u16*)w;  w += (size_t)BATCH * NH * BHSZ * 2;   // 8 MB
  u16* Qf     = (u16*)w;  w += (size_t)BATCH * NH * BHSZ * 2;   // 8 MB
  u16* nudged = (u16*)w;  w += (size_t)MROWS * CDIM * 2;        // 8 MB

  hipLaunchKernelGGL(cvt_metric, dim3(768), dim3(256), 0, stream,
                     Wproj, Wmix, premet, wp_bf, wm_bf, metric);
  hipLaunchKernelGGL((gemm_xwt<0>), dim3(MROWS / 128, CDIM / 64), dim3(256), 0, stream,
                     (const u16*)x, wp_bf, (void*)Kf, Vf, metric, Qf, MROWS, CDIM, CDIM);
  hipLaunchKernelGGL(attn_kernel, dim3(32, 64), dim3(256), 0, stream,
                     Qf, Kf, Vf, nudged);
  hipLaunchKernelGGL((gemm_xwt<1>), dim3(MROWS / 128, CDIM / 64), dim3(256), 0, stream,
                     nudged, wm_bf, d_out, nullptr, nullptr, nullptr, MROWS, CDIM, CDIM);
}

// Round 24
// 86.099 us; speedup vs baseline: 1.0162x; 1.0162x over previous
//
#include <hip/hip_runtime.h>
#include <stdint.h>
#include <stddef.h>

typedef unsigned short u16;
typedef unsigned int u32;
typedef __attribute__((ext_vector_type(8))) __bf16 bf16x8;
typedef __attribute__((ext_vector_type(4))) float f32x4;
typedef __attribute__((ext_vector_type(16))) float f32x16;

#define DEV __device__ __forceinline__

// ---- problem dims (hardcoded per reference) ----
#define BATCH 2
#define SEQ   2048
#define CDIM  1024
#define NH    16
#define KD    64
#define MROWS (BATCH * SEQ)   // 4096
#define NX (MROWS * CDIM)     // 4194304
#define NW (CDIM * CDIM)      // 1048576
#define BHSZ  131072          // SEQ*KD u16 per (b,h)

DEV u16 f32_to_bf16(float f) {
  union { float f; unsigned u; } v; v.f = f;
  return (u16)((v.u + 0x7fffu + ((v.u >> 16) & 1u)) >> 16);
}
DEV u32 pack_bf16x2(float a, float b) {
  union { __bf16 h[2]; u32 u; } r;
  r.h[0] = (__bf16)a; r.h[1] = (__bf16)b;
  return r.u;
}
// truncation pack: low16 = hi16(a), high16 = hi16(b) -- single v_perm_b32
DEV u32 pack_trunc(float a, float b) {
  return __builtin_amdgcn_perm(__float_as_uint(b), __float_as_uint(a), 0x07060302u);
}
// raw 2^x (single v_exp_f32, no OCML wrapper)
DEV float v_exp2(float x) {
  float r; asm("v_exp_f32 %0, %1" : "=v"(r) : "v"(x)); return r;
}

// async global->LDS, 16B per lane
DEV void gl_lds16(const u16* g, u16* l) {
  __builtin_amdgcn_global_load_lds(
      (const __attribute__((address_space(1))) void*)(g),
      (__attribute__((address_space(3))) void*)(l), 16, 0, 0);
}

// ======================= fragment-linear layouts ==========================
// Kf stores K rows SIGMA-PERMUTED within each 32-row group (sigma = swap bits 2<->3
// of local kv, self-inverse): QK's S^T registers line up so s[8*ksl..8*ksl+7] IS the
// PV B-fragment pa[ksl] -- no cross-half exchange.
// Vf[bh][tile64][j=ksg*2+dh ][lane][8] = proj[tile64*64 + ksg*16 + (lane>>5)*8 + i][dh*32 + (lane&31)]
// Qf[bh][chunk][kc][lane][8]           = qm [chunk*32 + (lane&31)][kc*16 + (lane>>5)*8 + i] * cl2

// ---- fused: f32->bf16 convert (blocks 0..2047, TRUNC) + metric (2048..2303) ----
// R23 post-mortem: fusing x conversion into gemm<0> staging REGRESSED (reg-staged
// f32 path 41.6us vs gl_lds16 bf16; doubles A bytes + serial ds_writes). Keep the
// separate conversion pass (R21-proven best).
__global__ void cvt_metric(const float* __restrict__ x, const float* __restrict__ wp,
                           const float* __restrict__ wm, const float* __restrict__ pm,
                           u16* __restrict__ xb, u16* __restrict__ wpb,
                           u16* __restrict__ wmb, u16* __restrict__ metric) {
  __shared__ float P[64][65];
  int bid = blockIdx.x, t = threadIdx.x;
  if (bid < 2048) {
    int total4 = (NX + 2 * NW) >> 2;
    for (int i4 = bid * 256 + t; i4 < total4; i4 += 2048 * 256) {
      int i = i4 << 2;
      const float* src; u16* dst; int off;
      if (i < NX)           { src = x;  dst = xb;  off = i; }
      else if (i < NX + NW) { src = wp; dst = wpb; off = i - NX; }
      else                  { src = wm; dst = wmb; off = i - NX - NW; }
      float4 v = *reinterpret_cast<const float4*>(src + off);
      uint2 o;          // truncation: 2 v_perm instead of ~20 VALU for RNE
      o.x = pack_trunc(v.x, v.y);
      o.y = pack_trunc(v.z, v.w);
      *reinterpret_cast<uint2*>(dst + off) = o;
    }
    return;
  }
  int mb = bid - 2048;
  int h = mb >> 4, jgrp = mb & 15;
  if (t < 64) {
    int i = t;
    const float* row = pm + (size_t)(h * 64 + i) * 64;
    float mx = -1e30f;
    for (int j = 0; j <= i; ++j) mx = fmaxf(mx, row[j] * 0.125f);
    float s = 0.f;
    for (int j = 0; j <= i; ++j) { float e = expf(row[j] * 0.125f - mx); P[i][j] = e; s += e; }
    float inv = 1.f / s;
    for (int j = 0; j <= i; ++j) P[i][j] *= inv;
    for (int j = i + 1; j < 64; ++j) P[i][j] = 0.f;
  }
  __syncthreads();
  {
    int i = t & 63, jq = t >> 6;
    int j = jgrp * 4 + jq;
    float acc = 0.f;
    #pragma unroll
    for (int l = 0; l < 64; ++l) acc += P[i][l] * P[j][l];
    metric[(size_t)h * 4096 + i * 64 + j] = f32_to_bf16(acc);
  }
}

// ---------------- bf16 MFMA GEMM: C = A @ B^T, 128Mx64N tile, BK=64, 512 blocks ----
// GRID AXES SWAPPED (T1): blockIdx.x = M-tile, blockIdx.y = N-tile -> XCD = mx % 8:
// each XCD caches its 4 A-panels (1MB) + full B (2MB) in its 4MB L2.
// T3-minimum 2-phase: double-buffered LDS; stage(k+1) BEFORE compute(k); one barrier
// per k-step. LDS XOR-swizzled (T2, rule #21).
// MODE 0: N-tile == one head; writes Kf (sigma lane slots) / Vf (uint2-packed) +
//         fused qm epilogue -> Qf (Pl/Ml alias the dbuf).  MODE 1: f32 C0.
template <int MODE>
__launch_bounds__(256)
__global__ void gemm_xwt(const u16* __restrict__ A, const u16* __restrict__ B,
                         void* __restrict__ C0, u16* __restrict__ C1,
                         const u16* __restrict__ Mbf, u16* __restrict__ Qf,
                         int M, int N, int K) {
  __shared__ __align__(16) u16 SM[2 * 12288];   // 48KB: 2 x (A[128][64] + B[64][64])
  int bm0 = blockIdx.x * 128, bn0 = blockIdx.y * 64;
  int t = threadIdx.x, wv = t >> 6, lane = t & 63;
  int l15 = lane & 15, l4 = lane >> 4;
  f32x4 acc[2][4] = {};

  const int r8 = lane >> 3;                 // 0..7 (row within 8-row group)
  const int sseg = ((lane & 7) ^ r8) * 8;   // pre-swizzled source column (u16)

  auto stage = [&](int k0, u16* dst) {
    #pragma unroll
    for (int q = 0; q < 4; ++q) {
      int rowl = q * 32 + wv * 8;
      gl_lds16(A + (size_t)(bm0 + rowl + r8) * K + k0 + sseg, dst + rowl * 64);
    }
    u16* dstB = dst + 8192;
    #pragma unroll
    for (int q = 0; q < 2; ++q) {
      int rowl = q * 32 + wv * 8;
      gl_lds16(B + (size_t)(bn0 + rowl + r8) * K + k0 + sseg, dstB + rowl * 64);
    }
  };

  stage(0, SM);
  __syncthreads();
  const int NKS = K >> 6;
  for (int ks = 0; ks < NKS; ++ks) {
    u16* cur = SM + (ks & 1) * 12288;
    if (ks + 1 < NKS) stage((ks + 1) * 64, SM + ((ks + 1) & 1) * 12288);
    const u16* As = cur;
    const u16* Bs = cur + 8192;
    #pragma unroll
    for (int kk = 0; kk < 2; ++kk) {
      bf16x8 af[2], bfm[4];
      #pragma unroll
      for (int m = 0; m < 2; ++m) {
        int R = wv * 32 + m * 16 + l15;
        af[m] = *reinterpret_cast<const bf16x8*>(As + R * 64 + ((kk * 4 + l4) ^ (R & 7)) * 8);
      }
      #pragma unroll
      for (int nn = 0; nn < 4; ++nn) {
        int R = nn * 16 + l15;
        bfm[nn] = *reinterpret_cast<const bf16x8*>(Bs + R * 64 + ((kk * 4 + l4) ^ (R & 7)) * 8);
      }
      #pragma unroll
      for (int m = 0; m < 2; ++m)
        #pragma unroll
        for (int nn = 0; nn < 4; ++nn)
          acc[m][nn] = __builtin_amdgcn_mfma_f32_16x16x32_bf16(af[m], bfm[nn], acc[m][nn], 0, 0, 0);
    }
    __syncthreads();   // drains vmcnt: next-tile loads completed under this compute
  }

  if (MODE == 0) {
    int h = bn0 >> 6, bb = bm0 >> 11;
    size_t base = (size_t)(bb * NH + h) * BHSZ;
    u16* Pl = SM;            // [128][72] bf16 proj tile (A-frags for qm)
    u16* Ml = SM + 9216;     // [64][72]  bf16 metric    (B-frags for qm)
    // stage metric[h] into LDS (safe: k-loop ended with barrier)
    #pragma unroll
    for (int it = 0; it < 2; ++it) {
      int i = t * 8 + it * 2048;
      int r = i >> 6, c8 = i & 63;
      *reinterpret_cast<uint4*>(Ml + r * 72 + c8) =
          *reinterpret_cast<const uint4*>(Mbf + h * 4096 + i);
    }
    // fragment stores: Kf (sigma lane slots), Vf (uint2-packed) + P tile (LDS)
    #pragma unroll
    for (int m = 0; m < 2; ++m) {
      #pragma unroll
      for (int nn = 0; nn < 4; ++nn) {
        u16 hv4[4];
        #pragma unroll
        for (int rr = 0; rr < 4; ++rr) {
          int rowl = wv * 32 + m * 16 + l4 * 4 + rr;      // local row 0..127
          int d = nn * 16 + l15;
          u16 hv = f32_to_bf16(acc[m][nn][rr]);
          hv4[rr] = hv;
          int w2 = (bm0 & 2047) + rowl;
          int tile = w2 >> 6, rt = w2 & 63;
          int rl = rt & 31;
          // sigma: swap bits 2<->3 of local kv (self-inverse)
          int rls = (rl & 19) | ((rl & 4) << 1) | ((rl & 8) >> 1);
          // Kf: j=(d>>4)*2+(rt>>5), l=rls|(((d>>3)&1)<<5), i=d&7
          ((u16*)C0)[base + (size_t)(tile * 8 + (d >> 4) * 2 + (rt >> 5)) * 512
                     + (rls | (((d >> 3) & 1) << 5)) * 8 + (d & 7)] = hv;
          Pl[rowl * 72 + d] = hv;
        }
        // Vf packed: i = rt&7 contiguous across rr; one 8B store replaces 4 scatters
        {
          int rowl0 = wv * 32 + m * 16 + l4 * 4;
          int d = nn * 16 + l15;
          int w20 = (bm0 & 2047) + rowl0;
          int tile = w20 >> 6, rt0 = w20 & 63;
          uint2 vv;
          vv.x = (u32)hv4[0] | ((u32)hv4[1] << 16);
          vv.y = (u32)hv4[2] | ((u32)hv4[3] << 16);
          *reinterpret_cast<uint2*>(
              C1 + base + (size_t)(tile * 8 + ((rt0 >> 4) & 3) * 2 + (d >> 5)) * 512
                 + ((d & 31) | (((rt0 >> 3) & 1) << 5)) * 8 + (rt0 & 7)) = vv;
        }
      }
    }
    __syncthreads();
    // fused qm: qm_tile = P[128x64] @ M[64x64] (M symmetric -> B-frags = M rows)
    const float cl2 = 0.125f * 1.44269504088896f;
    f32x4 acc2[2][4] = {};
    #pragma unroll
    for (int kk2 = 0; kk2 < 2; ++kk2) {
      bf16x8 af2[2], bm2[4];
      #pragma unroll
      for (int m = 0; m < 2; ++m)
        af2[m] = *reinterpret_cast<const bf16x8*>(Pl + (wv * 32 + m * 16 + l15) * 72 + kk2 * 32 + l4 * 8);
      #pragma unroll
      for (int nn = 0; nn < 4; ++nn)
        bm2[nn] = *reinterpret_cast<const bf16x8*>(Ml + (nn * 16 + l15) * 72 + kk2 * 32 + l4 * 8);
      #pragma unroll
      for (int m = 0; m < 2; ++m)
        #pragma unroll
        for (int nn = 0; nn < 4; ++nn)
          acc2[m][nn] = __builtin_amdgcn_mfma_f32_16x16x32_bf16(af2[m], bm2[nn], acc2[m][nn], 0, 0, 0);
    }
    // Qf scatter store (pre-scaled by cl2)
    #pragma unroll
    for (int m = 0; m < 2; ++m) {
      #pragma unroll
      for (int nn = 0; nn < 4; ++nn) {
        #pragma unroll
        for (int rr = 0; rr < 4; ++rr) {
          int rowl = wv * 32 + m * 16 + l4 * 4 + rr;
          int d = nn * 16 + l15;
          int w2 = (bm0 & 2047) + rowl;
          Qf[base + (size_t)((w2 >> 5) * 4 + (d >> 4)) * 512
             + ((w2 & 31) | (((d >> 3) & 1) << 5)) * 8 + (d & 7)]
              = f32_to_bf16(acc2[m][nn][rr] * cl2);
        }
      }
    }
  } else {
    #pragma unroll
    for (int m = 0; m < 2; ++m) {
      int rbase = bm0 + wv * 32 + m * 16 + l4 * 4;
      #pragma unroll
      for (int nn = 0; nn < 4; ++nn) {
        int col = bn0 + nn * 16 + l15;
        #pragma unroll
        for (int rr = 0; rr < 4; ++rr)
          ((float*)C0)[(size_t)(rbase + rr) * N + col] = acc[m][nn][rr];
      }
    }
  }
}

// ---------------- causal flash attention: KVBLK=32, 4-way kv split, one chunk/block --
// grid (32 bh, 64 chunk [LPT]); bh -> XCD affinity optimal (32 % 8 == 0).
// sigma-permuted Kf => s[8*ksl..8*ksl+7] IS the PV B-frag: no exchange, no shfl.
// Groupwise softmax->PV (R21-proven best; R17/R20/R22 in-wave variants all neutral).
// __launch_bounds__(256,4): 128-unified-reg cap -> 4 waves/SIMD (R18-validated).
__launch_bounds__(256, 4)
__global__ void attn_kernel(const u16* __restrict__ Qf, const u16* __restrict__ Kf,
                            const u16* __restrict__ Vf, u16* __restrict__ nudged) {
  const int bh = blockIdx.x;
  const int bb = bh >> 4, h = bh & 15;
  const int p = 63 - (int)blockIdx.y;      // chunk (longest dispatched first)
  const int t = threadIdx.x, wv = t >> 6, lane = t & 63;
  const int c = lane & 31, hi = lane >> 5;
  const int q0 = p * 32;

  __shared__ float smf[4][2176];   // per warp: O^T[64][33] + l[32]@2112

  const u16* __restrict__ Kbh = Kf + (size_t)bh * BHSZ;
  const u16* __restrict__ Vbh = Vf + (size_t)bh * BHSZ;

  // Q fragments (coalesced 16B/lane), pre-scaled by cl2
  bf16x8 qf[4];
  {
    const u16* __restrict__ Qb = Qf + (size_t)bh * BHSZ + p * 2048 + lane * 8;
    #pragma unroll
    for (int kc = 0; kc < 4; ++kc)
      qf[kc] = *reinterpret_cast<const bf16x8*>(Qb + kc * 512);
  }

  f32x16 o0 = {}, o1 = {};
  float sv0 = 0.f, sv1 = 0.f;

  const int half = wv & 1;
  // current-tile offsets into Kf / Vf (u16 units); tile T: tile64 = T>>1
  u32 koff = (u32)((wv >> 1) * 4096 + half * 512 + lane * 8);
  u32 voff = (u32)((wv >> 1) * 4096 + half * 2048 + lane * 8);

  bf16x8 kf[4], vf0[2], vf1[2];
  if (wv <= p) {
    #pragma unroll
    for (int kc = 0; kc < 4; ++kc)
      kf[kc] = *reinterpret_cast<const bf16x8*>(Kbh + koff + kc * 1024);
    #pragma unroll
    for (int ksl = 0; ksl < 2; ++ksl) {
      vf0[ksl] = *reinterpret_cast<const bf16x8*>(Vbh + voff + ksl * 1024);
      vf1[ksl] = *reinterpret_cast<const bf16x8*>(Vbh + voff + ksl * 1024 + 512);
    }
  }

  for (int T = wv; T <= p; T += 4) {
    // S^T[kv=32][q=32] = K @ qm^T (lane c owns q-col c; rows sigma-permuted)
    f32x16 s = {};
    __builtin_amdgcn_s_setprio(1);
    #pragma unroll
    for (int kc = 0; kc < 4; ++kc)
      s = __builtin_amdgcn_mfma_f32_32x32x16_bf16(kf[kc], qf[kc], s, 0, 0, 0);
    __builtin_amdgcn_s_setprio(0);
    // K-regs dead: reload next tile now (in flight under softmax + PV)
    if (T + 4 <= p) {
      #pragma unroll
      for (int kc = 0; kc < 4; ++kc)
        kf[kc] = *reinterpret_cast<const bf16x8*>(Kbh + koff + 8192 + kc * 1024);
    }
    // causal mask (diagonal tile only): s[r] holds kv = sigma(row) per lane
    if (T == p) {
      #pragma unroll
      for (int r = 0; r < 16; ++r) {
        int kvl = (r & 3) + 4 * ((r >> 2) & 1) + 8 * hi + 16 * (r >> 3);
        if (kvl > c) s[r] = -1e30f;
      }
    }
    // groupwise softmax+PV: process ksl group 0 fully, then group 1.
    #pragma unroll
    for (int ksl = 0; ksl < 2; ++ksl) {
      float a = v_exp2(s[ksl * 8 + 0]);
      float b = v_exp2(s[ksl * 8 + 1]);
      float cc = v_exp2(s[ksl * 8 + 2]);
      float d = v_exp2(s[ksl * 8 + 3]);
      float e = v_exp2(s[ksl * 8 + 4]);
      float f = v_exp2(s[ksl * 8 + 5]);
      float g2 = v_exp2(s[ksl * 8 + 6]);
      float h2 = v_exp2(s[ksl * 8 + 7]);
      union { u32 u[4]; bf16x8 v; } pk;
      pk.u[0] = pack_trunc(a, b);
      pk.u[1] = pack_trunc(cc, d);
      pk.u[2] = pack_trunc(e, f);
      pk.u[3] = pack_trunc(g2, h2);
      __builtin_amdgcn_s_setprio(1);
      o0 = __builtin_amdgcn_mfma_f32_32x32x16_bf16(vf0[ksl], pk.v, o0, 0, 0, 0);
      o1 = __builtin_amdgcn_mfma_f32_32x32x16_bf16(vf1[ksl], pk.v, o1, 0, 0, 0);
      __builtin_amdgcn_s_setprio(0);
      sv0 += (a + b) + (cc + d);
      sv1 += (e + f) + (g2 + h2);
    }
    // V-regs dead: reload next tile now (in flight under next QK)
    if (T + 4 <= p) {
      #pragma unroll
      for (int ksl = 0; ksl < 2; ++ksl) {
        vf0[ksl] = *reinterpret_cast<const bf16x8*>(Vbh + voff + 8192 + ksl * 1024);
        vf1[ksl] = *reinterpret_cast<const bf16x8*>(Vbh + voff + 8192 + ksl * 1024 + 512);
      }
    }
    koff += 8192; voff += 8192;
  }

  // per-q-row sum (cross-half: other 16 kv of this q live in partner lane)
  float lrow;
  {
    float s2 = sv0 + sv1;
    lrow = s2 + __shfl_xor(s2, 32);
  }

  // ---- publish partials, then all-thread 4-way merge + coalesced store ----
  {
    float* Ob = smf[wv];
    #pragma unroll
    for (int r = 0; r < 16; ++r) {
      int d = (r & 3) + 8 * (r >> 2) + 4 * hi;
      Ob[d * 33 + c] = o0[r];
      Ob[(d + 32) * 33 + c] = o1[r];
    }
    if (hi == 0) Ob[2112 + c] = lrow;
  }
  __syncthreads();
  {
    int q = t >> 3, dseg = t & 7;
    float lsum = smf[0][2112 + q] + smf[1][2112 + q] + smf[2][2112 + q] + smf[3][2112 + q];
    float invd = 1.f / lsum;
    u16 outv[8];
    #pragma unroll
    for (int i2 = 0; i2 < 8; ++i2) {
      int d = dseg * 8 + i2;
      float v = smf[0][d * 33 + q] + smf[1][d * 33 + q] + smf[2][d * 33 + q] + smf[3][d * 33 + q];
      outv[i2] = f32_to_bf16(v * invd);
    }
    u16* dstp = nudged + ((size_t)bb * SEQ + q0 + q) * CDIM + h * KD + dseg * 8;
    uint4 ov;
    ov.x = (u32)outv[0] | ((u32)outv[1] << 16);
    ov.y = (u32)outv[2] | ((u32)outv[3] << 16);
    ov.z = (u32)outv[4] | ((u32)outv[5] << 16);
    ov.w = (u32)outv[6] | ((u32)outv[7] << 16);
    *reinterpret_cast<uint4*>(dstp) = ov;
  }
}

// ---------------- host launch ----------------
extern "C" void kernel_launch(void* const* d_in, const int* in_sizes, int n_in,
                              void* d_out, int out_size, void* d_ws, size_t ws_size,
                              hipStream_t stream) {
  (void)in_sizes; (void)n_in; (void)out_size; (void)ws_size;
  const float* x      = (const float*)d_in[0];
  const float* Wproj  = (const float*)d_in[1];
  const float* premet = (const float*)d_in[2];
  const float* Wmix   = (const float*)d_in[3];

  char* w = (char*)d_ws;
  u16* x_bf   = (u16*)w;  w += (size_t)MROWS * CDIM * 2;        // 8 MB
  u16* wp_bf  = (u16*)w;  w += (size_t)CDIM * CDIM * 2;         // 2 MB
  u16* wm_bf  = (u16*)w;  w += (size_t)CDIM * CDIM * 2;         // 2 MB
  u16* metric = (u16*)w;  w += (size_t)NH * KD * KD * 2;        // 128 KB
  u16* Kf     = (u16*)w;  w += (size_t)BATCH * NH * BHSZ * 2;   // 8 MB
  u16* Vf     = (u16*)w;  w += (size_t)BATCH * NH * BHSZ * 2;   // 8 MB
  u16* Qf     = (u16*)w;  w += (size_t)BATCH * NH * BHSZ * 2;   // 8 MB
  u16* nudged = (u16*)w;  w += (size_t)MROWS * CDIM * 2;        // 8 MB

  hipLaunchKernelGGL(cvt_metric, dim3(2304), dim3(256), 0, stream,
                     x, Wproj, Wmix, premet, x_bf, wp_bf, wm_bf, metric);
  hipLaunchKernelGGL((gemm_xwt<0>), dim3(MROWS / 128, CDIM / 64), dim3(256), 0, stream,
                     x_bf, wp_bf, (void*)Kf, Vf, metric, Qf, MROWS, CDIM, CDIM);
  hipLaunchKernelGGL(attn_kernel, dim3(32, 64), dim3(256), 0, stream,
                     Qf, Kf, Vf, nudged);
  hipLaunchKernelGGL((gemm_xwt<1>), dim3(MROWS / 128, CDIM / 64), dim3(256), 0, stream,
                     nudged, wm_bf, d_out, nullptr, nullptr, nullptr, MROWS, CDIM, CDIM);
}